// Round 9
// baseline (673.269 us; speedup 1.0000x reference)
//
#include <hip/hip_runtime.h>
#include <hip/hip_bf16.h>
#include <math.h>

#define BQ 8
#define LQ 1024
#define DMODEL 256
#define DINNER 512
#define DSTATE 16
#define NLAYER 4
#define NTOK (BQ * LQ)          // 8192
#define NCHUNK 16
#define CHLEN 64

typedef __attribute__((ext_vector_type(8))) short short8v;
typedef __attribute__((ext_vector_type(4))) float float4v;
typedef __attribute__((ext_vector_type(4))) short short4v;

// ---------------- helpers ----------------

__device__ inline float silu_f(float x) { return x / (1.f + __expf(-x)); }

__device__ inline float softplus_f(float x) {
    return (x > 20.f) ? x : log1pf(expf(x));
}

__device__ __forceinline__ float bf2f(short v) {
    union { unsigned u; float f; } x;
    x.u = ((unsigned)(unsigned short)v) << 16;
    return x.f;
}

__device__ __forceinline__ void gl_lds16(const void* g, void* l) {
    __builtin_amdgcn_global_load_lds(
        (const __attribute__((address_space(1))) unsigned int*)g,
        (__attribute__((address_space(3))) unsigned int*)l,
        16, 0, 0);
}

// block-wide mean / rstd over 256 values (one per thread)
__device__ inline float2 block_meanrstd(float v, float* sbuf) {
    float sm = v, sq = v * v;
#pragma unroll
    for (int o = 32; o; o >>= 1) {
        sm += __shfl_xor(sm, o);
        sq += __shfl_xor(sq, o);
    }
    int w = threadIdx.x >> 6;
    if ((threadIdx.x & 63) == 0) { sbuf[w] = sm; sbuf[4 + w] = sq; }
    __syncthreads();
    sm = sbuf[0] + sbuf[1] + sbuf[2] + sbuf[3];
    sq = sbuf[4] + sbuf[5] + sbuf[6] + sbuf[7];
    float m = sm * (1.f / 256.f);
    float var = sq * (1.f / 256.f) - m * m;
    return make_float2(m, rsqrtf(var + 1e-5f));
}

// ---------------- fused weight prep ----------------
// transpose+cast tile helper: in [K][N] f32 -> out [N][K] bf16, 32x32 tile (kt,nt)
__device__ __forceinline__ void tr_tile(const float* __restrict__ inp,
                                        __hip_bfloat16* __restrict__ outp,
                                        int K, int N, int kt, int nt,
                                        float (*t)[33]) {
    int k0 = kt * 32, n0 = nt * 32;
    int tx = threadIdx.x & 31, ty = threadIdx.x >> 5;
#pragma unroll
    for (int i = 0; i < 32; i += 8) {
        int k = k0 + ty + i, n = n0 + tx;
        t[ty + i][tx] = (n < N) ? inp[(size_t)k * N + n] : 0.f;
    }
    __syncthreads();
#pragma unroll
    for (int i = 0; i < 32; i += 8) {
        int n = n0 + ty + i, k = k0 + tx;
        if (n < N) outp[(size_t)n * K + k] = __float2bfloat16(t[tx][ty + i]);
    }
}

// one kernel: W_inproj^T, W_dt^T, W_B^T, W_C^T, W_out^T + zero-pad W2p rows 544..639
__global__ __launch_bounds__(256) void k_prep(const float* __restrict__ Wi,
                                              const float* __restrict__ Wdt,
                                              const float* __restrict__ WB,
                                              const float* __restrict__ WC,
                                              const float* __restrict__ Wo,
                                              __hip_bfloat16* __restrict__ W1p,
                                              __hip_bfloat16* __restrict__ W2p,
                                              __hip_bfloat16* __restrict__ W3p) {
    __shared__ float t[32][33];
    int bid = blockIdx.x;
    if (bid < 1024) {                       // W_inproj [4][256][1024] -> [4][1024][256]
        int z = bid >> 8, r = bid & 255;
        tr_tile(Wi + (size_t)z * 262144, W1p + (size_t)z * 262144, 256, 1024, r & 7, r >> 3, t);
    } else if (bid < 2048) {                // W_dt [4][512][512] -> W2p rows 0..511
        int b2 = bid - 1024;
        int z = b2 >> 8, r = b2 & 255;
        tr_tile(Wdt + (size_t)z * 262144, W2p + (size_t)z * 327680, 512, 512, r & 15, r >> 4, t);
    } else if (bid < 2112) {                // W_B [4][512][16] -> W2p rows 512..527
        int b2 = bid - 2048;
        int z = b2 >> 4, r = b2 & 15;
        tr_tile(WB + (size_t)z * 8192, W2p + (size_t)z * 327680 + 512 * 512, 512, 16, r, 0, t);
    } else if (bid < 2176) {                // W_C -> W2p rows 528..543
        int b2 = bid - 2112;
        int z = b2 >> 4, r = b2 & 15;
        tr_tile(WC + (size_t)z * 8192, W2p + (size_t)z * 327680 + 528 * 512, 512, 16, r, 0, t);
    } else if (bid < 2688) {                // W_out [4][512][256] -> [4][256][512]
        int b2 = bid - 2176;
        int z = b2 >> 7, r = b2 & 127;
        tr_tile(Wo + (size_t)z * 131072, W3p + (size_t)z * 131072, 512, 256, r & 15, r >> 4, t);
    } else {                                // zero-pad W2p rows 544..639
        int b2 = bid - 2688;                // 0..95 (24 blocks/layer x 4KB)
        int z = b2 / 24, blk = b2 % 24;
        char* dst = (char*)(W2p + (size_t)z * 327680 + 544 * 512) + (size_t)blk * 4096;
        *(float4*)(dst + threadIdx.x * 16) = make_float4(0.f, 0.f, 0.f, 0.f);
    }
}

// ---------------- elementwise ----------------

__global__ __launch_bounds__(256) void k_inproj_ln(const float* __restrict__ x,
                                                   const float* __restrict__ w_in,
                                                   const float* __restrict__ b_in,
                                                   const float* __restrict__ g,
                                                   const float* __restrict__ bt,
                                                   float* __restrict__ h) {
    int tok = blockIdx.x;
    int b = tok >> 10, l = tok & 1023;
    int d = threadIdx.x;
    __shared__ float xs[4];
    __shared__ float sbuf[8];
    if (d < 4) xs[d] = x[((size_t)b * 4 + d) * LQ + l];
    __syncthreads();
    float v = b_in[d];
#pragma unroll
    for (int c = 0; c < 4; c++) v = fmaf(xs[c], w_in[d * 4 + c], v);
    float2 mr = block_meanrstd(v, sbuf);
    h[(size_t)tok * 256 + d] = (v - mr.x) * mr.y * g[d] + bt[d];
}

// wave-per-token LayerNorm (4 tokens/block, no block barrier)
__global__ __launch_bounds__(256) void k_ln(const float* __restrict__ h,
                                            const float* __restrict__ g,
                                            const float* __restrict__ bt,
                                            __hip_bfloat16* __restrict__ hn) {
    int tok = blockIdx.x * 4 + (threadIdx.x >> 6);
    int lane = threadIdx.x & 63;
    float4 v = *(const float4*)&h[(size_t)tok * 256 + lane * 4];
    float sm = v.x + v.y + v.z + v.w;
    float sq = v.x * v.x + v.y * v.y + v.z * v.z + v.w * v.w;
#pragma unroll
    for (int o = 32; o; o >>= 1) {
        sm += __shfl_xor(sm, o);
        sq += __shfl_xor(sq, o);
    }
    float m = sm * (1.f / 256.f);
    float rstd = rsqrtf(sq * (1.f / 256.f) - m * m + 1e-5f);
    float4 gv = *(const float4*)&g[lane * 4];
    float4 bv = *(const float4*)&bt[lane * 4];
    short4v o;
    __hip_bfloat16 r0 = __float2bfloat16((v.x - m) * rstd * gv.x + bv.x);
    __hip_bfloat16 r1 = __float2bfloat16((v.y - m) * rstd * gv.y + bv.y);
    __hip_bfloat16 r2 = __float2bfloat16((v.z - m) * rstd * gv.z + bv.z);
    __hip_bfloat16 r3 = __float2bfloat16((v.w - m) * rstd * gv.w + bv.w);
    o[0] = *(short*)&r0; o[1] = *(short*)&r1; o[2] = *(short*)&r2; o[3] = *(short*)&r3;
    *(short4v*)&hn[(size_t)tok * 256 + lane * 4] = o;
}

// causal depthwise conv, vectorized: each thread = 8 consecutive d of one token
__global__ __launch_bounds__(256) void k_conv(const __hip_bfloat16* __restrict__ xz,
                                              const float* __restrict__ cw,
                                              const float* __restrict__ cb,
                                              __hip_bfloat16* __restrict__ xs_out) {
    int i = blockIdx.x * 256 + threadIdx.x;   // over NTOK*64
    int d0 = (i & 63) * 8;
    int tok = i >> 6;
    int l = tok & 1023;
    int b = tok >> 10;
    const __hip_bfloat16* base = xz + ((size_t)b * 1024) * 1024 + d0;

    int l3 = l >= 3 ? l - 3 : 0, l2 = l >= 2 ? l - 2 : 0, l1 = l >= 1 ? l - 1 : 0;
    short8v v0 = *(const short8v*)&base[(size_t)l3 * 1024];
    short8v v1 = *(const short8v*)&base[(size_t)l2 * 1024];
    short8v v2 = *(const short8v*)&base[(size_t)l1 * 1024];
    short8v v3 = *(const short8v*)&base[(size_t)l * 1024];
    bool t0 = l >= 3, t1 = l >= 2, t2 = l >= 1;

    short8v o;
#pragma unroll
    for (int j = 0; j < 8; j++) {
        float4 wj = *(const float4*)&cw[(d0 + j) * 4];
        float a = cb[d0 + j];
        if (t0) a = fmaf(bf2f(v0[j]), wj.x, a);
        if (t1) a = fmaf(bf2f(v1[j]), wj.y, a);
        if (t2) a = fmaf(bf2f(v2[j]), wj.z, a);
        a = fmaf(bf2f(v3[j]), wj.w, a);
        __hip_bfloat16 r = __float2bfloat16(silu_f(a));
        o[j] = *(short*)&r;
    }
    *(short8v*)&xs_out[(size_t)tok * 512 + d0] = o;
}

// ---------------- MFMA GEMM (round-5 schedule, BM x BN tile) ----------------
// C[M,N](epi) = A[M,K](bf16,row-major) * Bp (bf16, n-major: Bp[n][k])
// 4 waves in 2x2: wave covers (BM/2) x (BN/2). BK=32, double-buffered,
// prefetch issued BEFORE compute, one barrier per iter (measured-best schedule).
template <int EPI, int BM, int BN>
__global__ __launch_bounds__(256) void k_mfma(const __hip_bfloat16* __restrict__ A,
                                              const __hip_bfloat16* __restrict__ Bp,
                                              void* __restrict__ Cv,
                                              const float* __restrict__ bias,
                                              float* __restrict__ outB,
                                              float* __restrict__ outC,
                                              int N, int K) {
    constexpr int BK = 32;
    constexpr int FM = BM / 32;               // M-frags per wave
    constexpr int FN = BN / 32;               // N-frags per wave
    constexpr int GA = BM / 16;               // 64-chunk staging groups in A
    constexpr int GB = BN / 16;               // ... in B
    constexpr int PW = (GA + GB) / 4;         // groups per wave

    __shared__ short As[2][BM * BK];
    __shared__ short Bs[2][BN * BK];
    const int tid = threadIdx.x;
    const int w = tid >> 6, l = tid & 63;
    const int bm = blockIdx.x * BM, bn = blockIdx.y * BN;
    const int wm = (w >> 1) * (BM / 2), wn = (w & 1) * (BN / 2);

    float4v acc[FM][FN];
#pragma unroll
    for (int i = 0; i < FM; i++)
#pragma unroll
        for (int j = 0; j < FN; j++) acc[i][j] = (float4v)0.f;

    const size_t Kb = (size_t)K * 2;
    const char* Ab = (const char*)A + (size_t)bm * Kb;
    const char* Bb = (const char*)Bp + (size_t)bn * Kb;
    const int lrow = l & 15;
    const int lk8 = (l >> 4) * 8;

    auto stage = [&](int buf, int k0) {
#pragma unroll
        for (int gi = 0; gi < PW; gi++) {
            int g = w * PW + gi;
            if (g < GA) {
                int c = g * 64 + l;
                gl_lds16(Ab + (size_t)(c >> 2) * Kb + (size_t)k0 * 2 + (c & 3) * 16,
                         (char*)&As[buf][0] + g * 1024);
            } else {
                int gg = g - GA;
                int c = gg * 64 + l;
                gl_lds16(Bb + (size_t)(c >> 2) * Kb + (size_t)k0 * 2 + (c & 3) * 16,
                         (char*)&Bs[buf][0] + gg * 1024);
            }
        }
    };

    stage(0, 0);
    __syncthreads();
    int cur = 0;
    for (int k0 = 0; k0 < K; k0 += BK) {
        if (k0 + BK < K) stage(cur ^ 1, k0 + BK);
        short8v af[FM], bf[FN];
#pragma unroll
        for (int mi = 0; mi < FM; mi++)
            af[mi] = *(const short8v*)&As[cur][(wm + mi * 16 + lrow) * BK + lk8];
#pragma unroll
        for (int ni = 0; ni < FN; ni++)
            bf[ni] = *(const short8v*)&Bs[cur][(wn + ni * 16 + lrow) * BK + lk8];
#pragma unroll
        for (int mi = 0; mi < FM; mi++)
#pragma unroll
            for (int ni = 0; ni < FN; ni++)
                acc[mi][ni] = __builtin_amdgcn_mfma_f32_16x16x32_bf16(
                    af[mi], bf[ni], acc[mi][ni], 0, 0, 0);
        __syncthreads();
        cur ^= 1;
    }

    const int lq = (l >> 4) * 4;
#pragma unroll
    for (int mi = 0; mi < FM; mi++) {
#pragma unroll
        for (int ni = 0; ni < FN; ni++) {
            int row0 = bm + wm + mi * 16 + lq;
            int col = bn + wn + ni * 16 + lrow;
            if (EPI == 0) {
                __hip_bfloat16* o = (__hip_bfloat16*)Cv;
#pragma unroll
                for (int r = 0; r < 4; r++)
                    o[(size_t)(row0 + r) * N + col] = __float2bfloat16(acc[mi][ni][r]);
            } else if (EPI == 1) {
                if (col < 512) {
                    __hip_bfloat16* o = (__hip_bfloat16*)Cv;
                    float bc = bias[col];
#pragma unroll
                    for (int r = 0; r < 4; r++)
                        o[(size_t)(row0 + r) * 512 + col] =
                            __float2bfloat16(softplus_f(acc[mi][ni][r] + bc));
                } else if (col < 528) {
#pragma unroll
                    for (int r = 0; r < 4; r++)
                        outB[(size_t)(row0 + r) * 16 + (col - 512)] = acc[mi][ni][r];
                } else if (col < 544) {
#pragma unroll
                    for (int r = 0; r < 4; r++)
                        outC[(size_t)(row0 + r) * 16 + (col - 528)] = acc[mi][ni][r];
                }
            } else {
                float* o = (float*)Cv;
#pragma unroll
                for (int r = 0; r < 4; r++)
                    o[(size_t)(row0 + r) * 256 + col] += acc[mi][ni][r];
            }
        }
    }
}

// ---------------- chunked selective scan (register-state form) ----------------

__global__ __launch_bounds__(256) void k_scanA(const __hip_bfloat16* __restrict__ xs,
                                               const __hip_bfloat16* __restrict__ dt,
                                               const float* __restrict__ Bin,
                                               const float* __restrict__ A_log,
                                               float* __restrict__ h_end,
                                               float* __restrict__ dtsum) {
    int bx = blockIdx.x;
    int dtile = bx & 7;
    int c = (bx >> 3) & 15;
    int b = bx >> 7;
    int lane = threadIdx.x & 63, wave = threadIdx.x >> 6;
    int d = dtile * 64 + lane;
    int s0 = wave * 4;

    float4 Ar = *(const float4*)&A_log[d * 16 + s0];
    float A0 = -__expf(Ar.x), A1 = -__expf(Ar.y), A2 = -__expf(Ar.z), A3 = -__expf(Ar.w);

    const size_t tok0 = (size_t)b * LQ + (size_t)c * CHLEN;
    const __hip_bfloat16* dt_p = dt + tok0 * 512 + d;
    const __hip_bfloat16* x_p  = xs + tok0 * 512 + d;
    const float* B_p = Bin + tok0 * 16 + s0;

    float h0 = 0.f, h1 = 0.f, h2 = 0.f, h3 = 0.f, dts = 0.f;

    const int U = 4;
    float dtA[U], xA[U]; float4 BA[U];
    float dtB[U], xB[U]; float4 BB[U];

    auto loadA = [&](int t0) {
#pragma unroll
        for (int j = 0; j < U; j++) {
            dtA[j] = __bfloat162float(dt_p[(size_t)(t0 + j) * 512]);
            xA[j]  = __bfloat162float(x_p[(size_t)(t0 + j) * 512]);
            BA[j]  = *(const float4*)&B_p[(size_t)(t0 + j) * 16];
        }
    };
    auto loadB = [&](int t0) {
#pragma unroll
        for (int j = 0; j < U; j++) {
            dtB[j] = __bfloat162float(dt_p[(size_t)(t0 + j) * 512]);
            xB[j]  = __bfloat162float(x_p[(size_t)(t0 + j) * 512]);
            BB[j]  = *(const float4*)&B_p[(size_t)(t0 + j) * 16];
        }
    };
    auto compA = [&]() {
#pragma unroll
        for (int j = 0; j < U; j++) {
            float dtv = dtA[j], u = dtv * xA[j];
            dts += dtv;
            h0 = fmaf(__expf(A0 * dtv), h0, u * BA[j].x);
            h1 = fmaf(__expf(A1 * dtv), h1, u * BA[j].y);
            h2 = fmaf(__expf(A2 * dtv), h2, u * BA[j].z);
            h3 = fmaf(__expf(A3 * dtv), h3, u * BA[j].w);
        }
    };
    auto compB = [&]() {
#pragma unroll
        for (int j = 0; j < U; j++) {
            float dtv = dtB[j], u = dtv * xB[j];
            dts += dtv;
            h0 = fmaf(__expf(A0 * dtv), h0, u * BB[j].x);
            h1 = fmaf(__expf(A1 * dtv), h1, u * BB[j].y);
            h2 = fmaf(__expf(A2 * dtv), h2, u * BB[j].z);
            h3 = fmaf(__expf(A3 * dtv), h3, u * BB[j].w);
        }
    };

    loadA(0);
    for (int t = 0; t < CHLEN; t += 2 * U) {
        loadB(t + U);
        compA();
        if (t + 2 * U < CHLEN) loadA(t + 2 * U);
        compB();
    }

    size_t cidx = (size_t)(b * NCHUNK + c) * 512 + d;
    *(float4*)&h_end[cidx * 16 + s0] = make_float4(h0, h1, h2, h3);
    if (wave == 0) dtsum[cidx] = dts;
}

// pass C with fused carry prologue: rebuild H_in from h_end/dtsum, then re-run
// recurrence and write gated y.
__global__ __launch_bounds__(256) void k_scanC(const __hip_bfloat16* __restrict__ xs,
                                               const __hip_bfloat16* __restrict__ dt,
                                               const float* __restrict__ Bin,
                                               const float* __restrict__ Cin,
                                               const float* __restrict__ A_log,
                                               const float* __restrict__ h_end,
                                               const float* __restrict__ dtsum,
                                               const __hip_bfloat16* __restrict__ xz,
                                               const float* __restrict__ Dv,
                                               __hip_bfloat16* __restrict__ y) {
    int bx = blockIdx.x;
    int dtile = bx & 7;
    int c = (bx >> 3) & 15;
    int b = bx >> 7;
    int lane = threadIdx.x & 63, wave = threadIdx.x >> 6;
    int sg = lane & 3, dl = lane >> 2;
    int d = dtile * 64 + wave * 16 + dl;
    int s0 = sg * 4;

    float4 Ar = *(const float4*)&A_log[d * 16 + s0];
    float A0 = -__expf(Ar.x), A1 = -__expf(Ar.y), A2 = -__expf(Ar.z), A3 = -__expf(Ar.w);

    // carry prologue: state entering chunk c (serial over previous chunks)
    float h0 = 0.f, h1 = 0.f, h2 = 0.f, h3 = 0.f;
    for (int cp = 0; cp < c; cp++) {
        size_t ci = (size_t)(b * NCHUNK + cp) * 512 + d;
        float4 he = *(const float4*)&h_end[ci * 16 + s0];
        float dts = dtsum[ci];
        h0 = fmaf(__expf(A0 * dts), h0, he.x);
        h1 = fmaf(__expf(A1 * dts), h1, he.y);
        h2 = fmaf(__expf(A2 * dts), h2, he.z);
        h3 = fmaf(__expf(A3 * dts), h3, he.w);
    }

    float Dd = Dv[d];

    const size_t tok0 = (size_t)b * LQ + (size_t)c * CHLEN;
    const __hip_bfloat16* dt_p = dt + tok0 * 512 + d;
    const __hip_bfloat16* x_p  = xs + tok0 * 512 + d;
    const __hip_bfloat16* z_p  = xz + tok0 * 1024 + 512 + d;
    const float* B_p = Bin + tok0 * 16 + s0;
    const float* C_p = Cin + tok0 * 16 + s0;
    __hip_bfloat16* y_p = y + tok0 * 512 + d;

    const int U = 4;
    float dtA[U], xA[U], zA[U]; float4 BA[U], CA[U];
    float dtB[U], xB[U], zB[U]; float4 BB[U], CB[U];

    auto loadA = [&](int t0) {
#pragma unroll
        for (int j = 0; j < U; j++) {
            dtA[j] = __bfloat162float(dt_p[(size_t)(t0 + j) * 512]);
            xA[j]  = __bfloat162float(x_p[(size_t)(t0 + j) * 512]);
            zA[j]  = __bfloat162float(z_p[(size_t)(t0 + j) * 1024]);
            BA[j]  = *(const float4*)&B_p[(size_t)(t0 + j) * 16];
            CA[j]  = *(const float4*)&C_p[(size_t)(t0 + j) * 16];
        }
    };
    auto loadB = [&](int t0) {
#pragma unroll
        for (int j = 0; j < U; j++) {
            dtB[j] = __bfloat162float(dt_p[(size_t)(t0 + j) * 512]);
            xB[j]  = __bfloat162float(x_p[(size_t)(t0 + j) * 512]);
            zB[j]  = __bfloat162float(z_p[(size_t)(t0 + j) * 1024]);
            BB[j]  = *(const float4*)&B_p[(size_t)(t0 + j) * 16];
            CB[j]  = *(const float4*)&C_p[(size_t)(t0 + j) * 16];
        }
    };
    auto compA = [&](int t0) {
#pragma unroll
        for (int j = 0; j < U; j++) {
            float dtv = dtA[j], u = dtv * xA[j];
            h0 = fmaf(__expf(A0 * dtv), h0, u * BA[j].x);
            h1 = fmaf(__expf(A1 * dtv), h1, u * BA[j].y);
            h2 = fmaf(__expf(A2 * dtv), h2, u * BA[j].z);
            h3 = fmaf(__expf(A3 * dtv), h3, u * BA[j].w);
            float yp = h0 * CA[j].x + h1 * CA[j].y + h2 * CA[j].z + h3 * CA[j].w;
            yp += __shfl_xor(yp, 1);
            yp += __shfl_xor(yp, 2);
            if (sg == 0)
                y_p[(size_t)(t0 + j) * 512] =
                    __float2bfloat16((yp + Dd * xA[j]) * silu_f(zA[j]));
        }
    };
    auto compB = [&](int t0) {
#pragma unroll
        for (int j = 0; j < U; j++) {
            float dtv = dtB[j], u = dtv * xB[j];
            h0 = fmaf(__expf(A0 * dtv), h0, u * BB[j].x);
            h1 = fmaf(__expf(A1 * dtv), h1, u * BB[j].y);
            h2 = fmaf(__expf(A2 * dtv), h2, u * BB[j].z);
            h3 = fmaf(__expf(A3 * dtv), h3, u * BB[j].w);
            float yp = h0 * CB[j].x + h1 * CB[j].y + h2 * CB[j].z + h3 * CB[j].w;
            yp += __shfl_xor(yp, 1);
            yp += __shfl_xor(yp, 2);
            if (sg == 0)
                y_p[(size_t)(t0 + j) * 512] =
                    __float2bfloat16((yp + Dd * xB[j]) * silu_f(zB[j]));
        }
    };

    loadA(0);
    for (int t = 0; t < CHLEN; t += 2 * U) {
        loadB(t + U);
        compA(t);
        if (t + 2 * U < CHLEN) loadA(t + 2 * U);
        compB(t + U);
    }
}

// per-token mean/rstd for final LN
__global__ __launch_bounds__(256) void k_stats(const float* __restrict__ h,
                                               float2* __restrict__ stats) {
    int tok = blockIdx.x * 4 + (threadIdx.x >> 6);
    int lane = threadIdx.x & 63;
    float4 v = *(const float4*)&h[(size_t)tok * 256 + lane * 4];
    float sm = v.x + v.y + v.z + v.w;
    float sq = v.x * v.x + v.y * v.y + v.z * v.z + v.w * v.w;
#pragma unroll
    for (int o = 32; o; o >>= 1) {
        sm += __shfl_xor(sm, o);
        sq += __shfl_xor(sq, o);
    }
    if (lane == 0) {
        float m = sm * (1.f / 256.f);
        float var = sq * (1.f / 256.f) - m * m;
        stats[tok] = make_float2(m, rsqrtf(var + 1e-5f));
    }
}

__global__ __launch_bounds__(256) void k_out(const float* __restrict__ h,
                                             const float2* __restrict__ stats,
                                             const float* __restrict__ g,
                                             const float* __restrict__ bias,
                                             float* __restrict__ out) {
    int b = blockIdx.x >> 3;
    int chunk = blockIdx.x & 7;
    int d = threadIdx.x;
    float accv = 0.f;
    for (int l = chunk * 128; l < chunk * 128 + 128; l++) {
        float2 st = stats[b * 1024 + l];
        accv += (h[((size_t)b * 1024 + l) * 256 + d] - st.x) * st.y;
    }
    float res = accv * g[d] * (1.f / 1024.f);
    if (chunk == 0) res += bias[d];
    atomicAdd(&out[b * 256 + d], res);
}

// ---------------- launch ----------------

extern "C" void kernel_launch(void* const* d_in, const int* in_sizes, int n_in,
                              void* d_out, int out_size, void* d_ws, size_t ws_size,
                              hipStream_t stream) {
    const float* x       = (const float*)d_in[0];
    const float* w_in    = (const float*)d_in[1];
    const float* b_in    = (const float*)d_in[2];
    const float* ln_in_g = (const float*)d_in[3];
    const float* ln_in_b = (const float*)d_in[4];
    const float* ln_g    = (const float*)d_in[5];
    const float* ln_b    = (const float*)d_in[6];
    const float* W_inproj= (const float*)d_in[7];
    const float* conv_w  = (const float*)d_in[8];
    const float* conv_b  = (const float*)d_in[9];
    const float* W_dt    = (const float*)d_in[10];
    const float* b_dt    = (const float*)d_in[11];
    const float* W_B     = (const float*)d_in[12];
    const float* W_C     = (const float*)d_in[13];
    const float* A_log   = (const float*)d_in[14];
    const float* Dp      = (const float*)d_in[15];
    const float* W_out   = (const float*)d_in[16];
    const float* ln_f_g  = (const float*)d_in[17];
    const float* ln_f_b  = (const float*)d_in[18];

    float* out = (float*)d_out;

    char* p = (char*)d_ws;
    auto alloc = [&](size_t bytes) { char* r = p; p += (bytes + 255) & ~(size_t)255; return r; };

    float* h            = (float*)alloc((size_t)NTOK * 256 * 4);
    __hip_bfloat16* hn  = (__hip_bfloat16*)alloc((size_t)NTOK * 256 * 2);
    __hip_bfloat16* xz  = (__hip_bfloat16*)alloc((size_t)NTOK * 1024 * 2);
    __hip_bfloat16* xs  = (__hip_bfloat16*)alloc((size_t)NTOK * 512 * 2);
    __hip_bfloat16* dtb = (__hip_bfloat16*)alloc((size_t)NTOK * 512 * 2);
    float* Bin          = (float*)alloc((size_t)NTOK * 16 * 4);
    float* Cin          = (float*)alloc((size_t)NTOK * 16 * 4);
    __hip_bfloat16* yb  = (__hip_bfloat16*)alloc((size_t)NTOK * 512 * 2);
    float2* stats       = (float2*)alloc((size_t)NTOK * 8);
    float* h_end        = (float*)alloc((size_t)BQ * NCHUNK * 512 * 16 * 4);
    float* dtsum        = (float*)alloc((size_t)BQ * NCHUNK * 512 * 4);
    __hip_bfloat16* W1p = (__hip_bfloat16*)alloc((size_t)NLAYER * 1024 * 256 * 2);
    __hip_bfloat16* W2p = (__hip_bfloat16*)alloc((size_t)NLAYER * 640 * 512 * 2);
    __hip_bfloat16* W3p = (__hip_bfloat16*)alloc((size_t)NLAYER * 256 * 512 * 2);

    hipMemsetAsync(d_out, 0, (size_t)out_size * sizeof(float), stream);

    k_prep<<<2784, 256, 0, stream>>>(W_inproj, W_dt, W_B, W_C, W_out, W1p, W2p, W3p);

    k_inproj_ln<<<NTOK, 256, 0, stream>>>(x, w_in, b_in, ln_in_g, ln_in_b, h);

    for (int l = 0; l < NLAYER; l++) {
        k_ln<<<NTOK / 4, 256, 0, stream>>>(h, ln_g + l * 256, ln_b + l * 256, hn);

        k_mfma<0, 128, 128><<<dim3(64, 8), 256, 0, stream>>>(
            hn, W1p + (size_t)l * 1024 * 256, xz, nullptr, nullptr, nullptr, 1024, 256);

        k_conv<<<(NTOK * 64) / 256, 256, 0, stream>>>(xz, conv_w + (size_t)l * 512 * 4,
                                                      conv_b + (size_t)l * 512, xs);

        k_mfma<1, 128, 128><<<dim3(64, 5), 256, 0, stream>>>(
            xs, W2p + (size_t)l * 640 * 512, dtb, b_dt + (size_t)l * 512, Bin, Cin, 576, 512);

        const float* Al = A_log + (size_t)l * 512 * 16;
        k_scanA<<<1024, 256, 0, stream>>>(xs, dtb, Bin, Al, h_end, dtsum);
        k_scanC<<<1024, 256, 0, stream>>>(xs, dtb, Bin, Cin, Al, h_end, dtsum, xz,
                                          Dp + (size_t)l * 512, yb);

        k_mfma<2, 64, 64><<<dim3(128, 4), 256, 0, stream>>>(
            yb, W3p + (size_t)l * 256 * 512, h, nullptr, nullptr, nullptr, 256, 512);
    }

    k_stats<<<NTOK / 4, 256, 0, stream>>>(h, stats);
    k_out<<<64, 256, 0, stream>>>(h, stats, ln_f_g, ln_f_b, out);
}

// Round 10
// 632.561 us; speedup vs baseline: 1.0644x; 1.0644x over previous
//
#include <hip/hip_runtime.h>
#include <hip/hip_bf16.h>
#include <math.h>

#define BQ 8
#define LQ 1024
#define DMODEL 256
#define DINNER 512
#define DSTATE 16
#define NLAYER 4
#define NTOK (BQ * LQ)          // 8192
#define NCHUNK 16
#define CHLEN 64

typedef __attribute__((ext_vector_type(8))) short short8v;
typedef __attribute__((ext_vector_type(4))) float float4v;
typedef __attribute__((ext_vector_type(4))) short short4v;

// ---------------- helpers ----------------

__device__ inline float silu_f(float x) { return x / (1.f + __expf(-x)); }

__device__ inline float softplus_f(float x) {
    return (x > 20.f) ? x : log1pf(expf(x));
}

__device__ __forceinline__ float bf2f(short v) {
    union { unsigned u; float f; } x;
    x.u = ((unsigned)(unsigned short)v) << 16;
    return x.f;
}

__device__ __forceinline__ void gl_lds16(const void* g, void* l) {
    __builtin_amdgcn_global_load_lds(
        (const __attribute__((address_space(1))) unsigned int*)g,
        (__attribute__((address_space(3))) unsigned int*)l,
        16, 0, 0);
}

// block-wide mean / rstd over 256 values (one per thread)
__device__ inline float2 block_meanrstd(float v, float* sbuf) {
    float sm = v, sq = v * v;
#pragma unroll
    for (int o = 32; o; o >>= 1) {
        sm += __shfl_xor(sm, o);
        sq += __shfl_xor(sq, o);
    }
    int w = threadIdx.x >> 6;
    if ((threadIdx.x & 63) == 0) { sbuf[w] = sm; sbuf[4 + w] = sq; }
    __syncthreads();
    sm = sbuf[0] + sbuf[1] + sbuf[2] + sbuf[3];
    sq = sbuf[4] + sbuf[5] + sbuf[6] + sbuf[7];
    float m = sm * (1.f / 256.f);
    float var = sq * (1.f / 256.f) - m * m;
    return make_float2(m, rsqrtf(var + 1e-5f));
}

// ---------------- fused weight prep ----------------
__device__ __forceinline__ void tr_tile(const float* __restrict__ inp,
                                        __hip_bfloat16* __restrict__ outp,
                                        int K, int N, int kt, int nt,
                                        float (*t)[33]) {
    int k0 = kt * 32, n0 = nt * 32;
    int tx = threadIdx.x & 31, ty = threadIdx.x >> 5;
#pragma unroll
    for (int i = 0; i < 32; i += 8) {
        int k = k0 + ty + i, n = n0 + tx;
        t[ty + i][tx] = (n < N) ? inp[(size_t)k * N + n] : 0.f;
    }
    __syncthreads();
#pragma unroll
    for (int i = 0; i < 32; i += 8) {
        int n = n0 + ty + i, k = k0 + tx;
        if (n < N) outp[(size_t)n * K + k] = __float2bfloat16(t[tx][ty + i]);
    }
}

// one kernel: W_inproj^T, W_dt^T, W_B^T, W_C^T, W_out^T + zero-pad W2p rows 544..639
__global__ __launch_bounds__(256) void k_prep(const float* __restrict__ Wi,
                                              const float* __restrict__ Wdt,
                                              const float* __restrict__ WB,
                                              const float* __restrict__ WC,
                                              const float* __restrict__ Wo,
                                              __hip_bfloat16* __restrict__ W1p,
                                              __hip_bfloat16* __restrict__ W2p,
                                              __hip_bfloat16* __restrict__ W3p) {
    __shared__ float t[32][33];
    int bid = blockIdx.x;
    if (bid < 1024) {
        int z = bid >> 8, r = bid & 255;
        tr_tile(Wi + (size_t)z * 262144, W1p + (size_t)z * 262144, 256, 1024, r & 7, r >> 3, t);
    } else if (bid < 2048) {
        int b2 = bid - 1024;
        int z = b2 >> 8, r = b2 & 255;
        tr_tile(Wdt + (size_t)z * 262144, W2p + (size_t)z * 327680, 512, 512, r & 15, r >> 4, t);
    } else if (bid < 2112) {
        int b2 = bid - 2048;
        int z = b2 >> 4, r = b2 & 15;
        tr_tile(WB + (size_t)z * 8192, W2p + (size_t)z * 327680 + 512 * 512, 512, 16, r, 0, t);
    } else if (bid < 2176) {
        int b2 = bid - 2112;
        int z = b2 >> 4, r = b2 & 15;
        tr_tile(WC + (size_t)z * 8192, W2p + (size_t)z * 327680 + 528 * 512, 512, 16, r, 0, t);
    } else if (bid < 2688) {
        int b2 = bid - 2176;
        int z = b2 >> 7, r = b2 & 127;
        tr_tile(Wo + (size_t)z * 131072, W3p + (size_t)z * 131072, 512, 256, r & 15, r >> 4, t);
    } else {
        int b2 = bid - 2688;                // 0..95
        int z = b2 / 24, blk = b2 % 24;
        char* dst = (char*)(W2p + (size_t)z * 327680 + 544 * 512) + (size_t)blk * 4096;
        *(float4*)(dst + threadIdx.x * 16) = make_float4(0.f, 0.f, 0.f, 0.f);
    }
}

// ---------------- elementwise ----------------

__global__ __launch_bounds__(256) void k_inproj_ln(const float* __restrict__ x,
                                                   const float* __restrict__ w_in,
                                                   const float* __restrict__ b_in,
                                                   const float* __restrict__ g,
                                                   const float* __restrict__ bt,
                                                   float* __restrict__ h) {
    int tok = blockIdx.x;
    int b = tok >> 10, l = tok & 1023;
    int d = threadIdx.x;
    __shared__ float xs[4];
    __shared__ float sbuf[8];
    if (d < 4) xs[d] = x[((size_t)b * 4 + d) * LQ + l];
    __syncthreads();
    float v = b_in[d];
#pragma unroll
    for (int c = 0; c < 4; c++) v = fmaf(xs[c], w_in[d * 4 + c], v);
    float2 mr = block_meanrstd(v, sbuf);
    h[(size_t)tok * 256 + d] = (v - mr.x) * mr.y * g[d] + bt[d];
}

// wave-per-token LayerNorm (4 tokens/block, no block barrier)
__global__ __launch_bounds__(256) void k_ln(const float* __restrict__ h,
                                            const float* __restrict__ g,
                                            const float* __restrict__ bt,
                                            __hip_bfloat16* __restrict__ hn) {
    int tok = blockIdx.x * 4 + (threadIdx.x >> 6);
    int lane = threadIdx.x & 63;
    float4 v = *(const float4*)&h[(size_t)tok * 256 + lane * 4];
    float sm = v.x + v.y + v.z + v.w;
    float sq = v.x * v.x + v.y * v.y + v.z * v.z + v.w * v.w;
#pragma unroll
    for (int o = 32; o; o >>= 1) {
        sm += __shfl_xor(sm, o);
        sq += __shfl_xor(sq, o);
    }
    float m = sm * (1.f / 256.f);
    float rstd = rsqrtf(sq * (1.f / 256.f) - m * m + 1e-5f);
    float4 gv = *(const float4*)&g[lane * 4];
    float4 bv = *(const float4*)&bt[lane * 4];
    short4v o;
    __hip_bfloat16 r0 = __float2bfloat16((v.x - m) * rstd * gv.x + bv.x);
    __hip_bfloat16 r1 = __float2bfloat16((v.y - m) * rstd * gv.y + bv.y);
    __hip_bfloat16 r2 = __float2bfloat16((v.z - m) * rstd * gv.z + bv.z);
    __hip_bfloat16 r3 = __float2bfloat16((v.w - m) * rstd * gv.w + bv.w);
    o[0] = *(short*)&r0; o[1] = *(short*)&r1; o[2] = *(short*)&r2; o[3] = *(short*)&r3;
    *(short4v*)&hn[(size_t)tok * 256 + lane * 4] = o;
}

// causal depthwise conv on dense x buffer [NTOK,512]; each thread = 8 d's
__global__ __launch_bounds__(256) void k_conv(const __hip_bfloat16* __restrict__ xbuf,
                                              const float* __restrict__ cw,
                                              const float* __restrict__ cb,
                                              __hip_bfloat16* __restrict__ xs_out) {
    int i = blockIdx.x * 256 + threadIdx.x;   // over NTOK*64
    int d0 = (i & 63) * 8;
    int tok = i >> 6;
    int l = tok & 1023;
    int b = tok >> 10;
    const __hip_bfloat16* base = xbuf + ((size_t)b * 1024) * 512 + d0;

    int l3 = l >= 3 ? l - 3 : 0, l2 = l >= 2 ? l - 2 : 0, l1 = l >= 1 ? l - 1 : 0;
    short8v v0 = *(const short8v*)&base[(size_t)l3 * 512];
    short8v v1 = *(const short8v*)&base[(size_t)l2 * 512];
    short8v v2 = *(const short8v*)&base[(size_t)l1 * 512];
    short8v v3 = *(const short8v*)&base[(size_t)l * 512];
    bool t0 = l >= 3, t1 = l >= 2, t2 = l >= 1;

    short8v o;
#pragma unroll
    for (int j = 0; j < 8; j++) {
        float4 wj = *(const float4*)&cw[(d0 + j) * 4];
        float a = cb[d0 + j];
        if (t0) a = fmaf(bf2f(v0[j]), wj.x, a);
        if (t1) a = fmaf(bf2f(v1[j]), wj.y, a);
        if (t2) a = fmaf(bf2f(v2[j]), wj.z, a);
        a = fmaf(bf2f(v3[j]), wj.w, a);
        __hip_bfloat16 r = __float2bfloat16(silu_f(a));
        o[j] = *(short*)&r;
    }
    *(short8v*)&xs_out[(size_t)tok * 512 + d0] = o;
}

// ---------------- MFMA GEMM (round-5 measured-best schedule) ----------------
// C[M,N](epi) = A[M,K](bf16,row-major) * Bp (bf16, n-major: Bp[n][k])
// 4 waves in 2x2: wave covers (BM/2) x 32. BK=32, double-buffered,
// prefetch issued BEFORE compute, one barrier per iteration.
// EPI 0: split store: col<512 -> xbuf bf16 [.,512]; col>=512 -> zbuf bf16 [.,512]
// EPI 1: col<512 -> dt=softplus(+bias) bf16; 512..527 -> Bin f32; 528..543 -> Cin f32
// EPI 2: C(f32)[.,256] += v
template <int EPI, int BM>
__global__ __launch_bounds__(256) void k_mfma(const __hip_bfloat16* __restrict__ A,
                                              const __hip_bfloat16* __restrict__ Bp,
                                              void* __restrict__ Cv,
                                              const float* __restrict__ bias,
                                              void* __restrict__ outB,
                                              float* __restrict__ outC,
                                              int N, int K) {
    constexpr int BN = 64, BK = 32;
    constexpr int FM = BM / 32;
    constexpr int GA = BM / 16;
    constexpr int GB = BN / 16;
    constexpr int PW = (GA + GB) / 4;

    __shared__ short As[2][BM * BK];
    __shared__ short Bs[2][BN * BK];
    const int tid = threadIdx.x;
    const int w = tid >> 6, l = tid & 63;
    const int bm = blockIdx.x * BM, bn = blockIdx.y * BN;
    const int wm = (w >> 1) * (BM / 2), wn = (w & 1) * 32;

    float4v acc[FM][2];
#pragma unroll
    for (int i = 0; i < FM; i++)
#pragma unroll
        for (int j = 0; j < 2; j++) acc[i][j] = (float4v)0.f;

    const size_t Kb = (size_t)K * 2;
    const char* Ab = (const char*)A + (size_t)bm * Kb;
    const char* Bb = (const char*)Bp + (size_t)bn * Kb;
    const int lrow = l & 15;
    const int lk8 = (l >> 4) * 8;

    auto stage = [&](int buf, int k0) {
#pragma unroll
        for (int gi = 0; gi < PW; gi++) {
            int g = w * PW + gi;
            if (g < GA) {
                int c = g * 64 + l;
                gl_lds16(Ab + (size_t)(c >> 2) * Kb + (size_t)k0 * 2 + (c & 3) * 16,
                         (char*)&As[buf][0] + g * 1024);
            } else {
                int gg = g - GA;
                int c = gg * 64 + l;
                gl_lds16(Bb + (size_t)(c >> 2) * Kb + (size_t)k0 * 2 + (c & 3) * 16,
                         (char*)&Bs[buf][0] + gg * 1024);
            }
        }
    };

    stage(0, 0);
    __syncthreads();
    int cur = 0;
    for (int k0 = 0; k0 < K; k0 += BK) {
        if (k0 + BK < K) stage(cur ^ 1, k0 + BK);
        short8v af[FM], bf[2];
#pragma unroll
        for (int mi = 0; mi < FM; mi++)
            af[mi] = *(const short8v*)&As[cur][(wm + mi * 16 + lrow) * BK + lk8];
#pragma unroll
        for (int ni = 0; ni < 2; ni++)
            bf[ni] = *(const short8v*)&Bs[cur][(wn + ni * 16 + lrow) * BK + lk8];
#pragma unroll
        for (int mi = 0; mi < FM; mi++)
#pragma unroll
            for (int ni = 0; ni < 2; ni++)
                acc[mi][ni] = __builtin_amdgcn_mfma_f32_16x16x32_bf16(
                    af[mi], bf[ni], acc[mi][ni], 0, 0, 0);
        __syncthreads();
        cur ^= 1;
    }

    const int lq = (l >> 4) * 4;
#pragma unroll
    for (int mi = 0; mi < FM; mi++) {
#pragma unroll
        for (int ni = 0; ni < 2; ni++) {
            int row0 = bm + wm + mi * 16 + lq;
            int col = bn + wn + ni * 16 + lrow;
            if (EPI == 0) {
                if (col < 512) {
                    __hip_bfloat16* o = (__hip_bfloat16*)Cv;
#pragma unroll
                    for (int r = 0; r < 4; r++)
                        o[(size_t)(row0 + r) * 512 + col] = __float2bfloat16(acc[mi][ni][r]);
                } else {
                    __hip_bfloat16* o = (__hip_bfloat16*)outB;
#pragma unroll
                    for (int r = 0; r < 4; r++)
                        o[(size_t)(row0 + r) * 512 + (col - 512)] = __float2bfloat16(acc[mi][ni][r]);
                }
            } else if (EPI == 1) {
                if (col < 512) {
                    __hip_bfloat16* o = (__hip_bfloat16*)Cv;
                    float bc = bias[col];
#pragma unroll
                    for (int r = 0; r < 4; r++)
                        o[(size_t)(row0 + r) * 512 + col] =
                            __float2bfloat16(softplus_f(acc[mi][ni][r] + bc));
                } else if (col < 528) {
                    float* o = (float*)outB;
#pragma unroll
                    for (int r = 0; r < 4; r++)
                        o[(size_t)(row0 + r) * 16 + (col - 512)] = acc[mi][ni][r];
                } else if (col < 544) {
#pragma unroll
                    for (int r = 0; r < 4; r++)
                        outC[(size_t)(row0 + r) * 16 + (col - 528)] = acc[mi][ni][r];
                }
            } else {
                float* o = (float*)Cv;
#pragma unroll
                for (int r = 0; r < 4; r++)
                    o[(size_t)(row0 + r) * 256 + col] += acc[mi][ni][r];
            }
        }
    }
}

// ---------------- chunked selective scan (register-state form) ----------------

__global__ __launch_bounds__(256) void k_scanA(const __hip_bfloat16* __restrict__ xs,
                                               const __hip_bfloat16* __restrict__ dt,
                                               const float* __restrict__ Bin,
                                               const float* __restrict__ A_log,
                                               float* __restrict__ h_end,
                                               float* __restrict__ dtsum) {
    int bx = blockIdx.x;
    int dtile = bx & 7;
    int c = (bx >> 3) & 15;
    int b = bx >> 7;
    int lane = threadIdx.x & 63, wave = threadIdx.x >> 6;
    int d = dtile * 64 + lane;
    int s0 = wave * 4;

    float4 Ar = *(const float4*)&A_log[d * 16 + s0];
    float A0 = -__expf(Ar.x), A1 = -__expf(Ar.y), A2 = -__expf(Ar.z), A3 = -__expf(Ar.w);

    const size_t tok0 = (size_t)b * LQ + (size_t)c * CHLEN;
    const __hip_bfloat16* dt_p = dt + tok0 * 512 + d;
    const __hip_bfloat16* x_p  = xs + tok0 * 512 + d;
    const float* B_p = Bin + tok0 * 16 + s0;

    float h0 = 0.f, h1 = 0.f, h2 = 0.f, h3 = 0.f, dts = 0.f;

    const int U = 4;
    float dtA[U], xA[U]; float4 BA[U];
    float dtB[U], xB[U]; float4 BB[U];

    auto loadA = [&](int t0) {
#pragma unroll
        for (int j = 0; j < U; j++) {
            dtA[j] = __bfloat162float(dt_p[(size_t)(t0 + j) * 512]);
            xA[j]  = __bfloat162float(x_p[(size_t)(t0 + j) * 512]);
            BA[j]  = *(const float4*)&B_p[(size_t)(t0 + j) * 16];
        }
    };
    auto loadB = [&](int t0) {
#pragma unroll
        for (int j = 0; j < U; j++) {
            dtB[j] = __bfloat162float(dt_p[(size_t)(t0 + j) * 512]);
            xB[j]  = __bfloat162float(x_p[(size_t)(t0 + j) * 512]);
            BB[j]  = *(const float4*)&B_p[(size_t)(t0 + j) * 16];
        }
    };
    auto compA = [&]() {
#pragma unroll
        for (int j = 0; j < U; j++) {
            float dtv = dtA[j], u = dtv * xA[j];
            dts += dtv;
            h0 = fmaf(__expf(A0 * dtv), h0, u * BA[j].x);
            h1 = fmaf(__expf(A1 * dtv), h1, u * BA[j].y);
            h2 = fmaf(__expf(A2 * dtv), h2, u * BA[j].z);
            h3 = fmaf(__expf(A3 * dtv), h3, u * BA[j].w);
        }
    };
    auto compB = [&]() {
#pragma unroll
        for (int j = 0; j < U; j++) {
            float dtv = dtB[j], u = dtv * xB[j];
            dts += dtv;
            h0 = fmaf(__expf(A0 * dtv), h0, u * BB[j].x);
            h1 = fmaf(__expf(A1 * dtv), h1, u * BB[j].y);
            h2 = fmaf(__expf(A2 * dtv), h2, u * BB[j].z);
            h3 = fmaf(__expf(A3 * dtv), h3, u * BB[j].w);
        }
    };

    loadA(0);
    for (int t = 0; t < CHLEN; t += 2 * U) {
        loadB(t + U);
        compA();
        if (t + 2 * U < CHLEN) loadA(t + 2 * U);
        compB();
    }

    size_t cidx = (size_t)(b * NCHUNK + c) * 512 + d;
    *(float4*)&h_end[cidx * 16 + s0] = make_float4(h0, h1, h2, h3);
    if (wave == 0) dtsum[cidx] = dts;
}

__global__ __launch_bounds__(256) void k_carry(const float* __restrict__ h_end,
                                               const float* __restrict__ dtsum,
                                               const float* __restrict__ A_log,
                                               float* __restrict__ H_in) {
    int idx = blockIdx.x * 256 + threadIdx.x;  // 65536 = 8*512*16
    int s = idx & 15;
    int d = (idx >> 4) & 511;
    int b = idx >> 13;
    float Av = -__expf(A_log[d * 16 + s]);
    float H = 0.f;
#pragma unroll
    for (int c = 0; c < NCHUNK; c++) {
        size_t cidx = (size_t)(b * NCHUNK + c) * 512 + d;
        H_in[cidx * 16 + s] = H;
        H = fmaf(__expf(Av * dtsum[cidx]), H, h_end[cidx * 16 + s]);
    }
}

__global__ __launch_bounds__(256) void k_scanC(const __hip_bfloat16* __restrict__ xs,
                                               const __hip_bfloat16* __restrict__ dt,
                                               const float* __restrict__ Bin,
                                               const float* __restrict__ Cin,
                                               const float* __restrict__ A_log,
                                               const float* __restrict__ H_in,
                                               const __hip_bfloat16* __restrict__ zbuf,
                                               const float* __restrict__ Dv,
                                               __hip_bfloat16* __restrict__ y) {
    int bx = blockIdx.x;
    int dtile = bx & 7;
    int c = (bx >> 3) & 15;
    int b = bx >> 7;
    int lane = threadIdx.x & 63, wave = threadIdx.x >> 6;
    int sg = lane & 3, dl = lane >> 2;
    int d = dtile * 64 + wave * 16 + dl;
    int s0 = sg * 4;

    float4 Ar = *(const float4*)&A_log[d * 16 + s0];
    float A0 = -__expf(Ar.x), A1 = -__expf(Ar.y), A2 = -__expf(Ar.z), A3 = -__expf(Ar.w);

    size_t cidx = (size_t)(b * NCHUNK + c) * 512 + d;
    float4 Hv = *(const float4*)&H_in[cidx * 16 + s0];
    float h0 = Hv.x, h1 = Hv.y, h2 = Hv.z, h3 = Hv.w;
    float Dd = Dv[d];

    const size_t tok0 = (size_t)b * LQ + (size_t)c * CHLEN;
    const __hip_bfloat16* dt_p = dt + tok0 * 512 + d;
    const __hip_bfloat16* x_p  = xs + tok0 * 512 + d;
    const __hip_bfloat16* z_p  = zbuf + tok0 * 512 + d;
    const float* B_p = Bin + tok0 * 16 + s0;
    const float* C_p = Cin + tok0 * 16 + s0;
    __hip_bfloat16* y_p = y + tok0 * 512 + d;

    const int U = 4;
    float dtA[U], xA[U], zA[U]; float4 BA[U], CA[U];
    float dtB[U], xB[U], zB[U]; float4 BB[U], CB[U];

    auto loadA = [&](int t0) {
#pragma unroll
        for (int j = 0; j < U; j++) {
            dtA[j] = __bfloat162float(dt_p[(size_t)(t0 + j) * 512]);
            xA[j]  = __bfloat162float(x_p[(size_t)(t0 + j) * 512]);
            zA[j]  = __bfloat162float(z_p[(size_t)(t0 + j) * 512]);
            BA[j]  = *(const float4*)&B_p[(size_t)(t0 + j) * 16];
            CA[j]  = *(const float4*)&C_p[(size_t)(t0 + j) * 16];
        }
    };
    auto loadB = [&](int t0) {
#pragma unroll
        for (int j = 0; j < U; j++) {
            dtB[j] = __bfloat162float(dt_p[(size_t)(t0 + j) * 512]);
            xB[j]  = __bfloat162float(x_p[(size_t)(t0 + j) * 512]);
            zB[j]  = __bfloat162float(z_p[(size_t)(t0 + j) * 512]);
            BB[j]  = *(const float4*)&B_p[(size_t)(t0 + j) * 16];
            CB[j]  = *(const float4*)&C_p[(size_t)(t0 + j) * 16];
        }
    };
    auto compA = [&](int t0) {
#pragma unroll
        for (int j = 0; j < U; j++) {
            float dtv = dtA[j], u = dtv * xA[j];
            h0 = fmaf(__expf(A0 * dtv), h0, u * BA[j].x);
            h1 = fmaf(__expf(A1 * dtv), h1, u * BA[j].y);
            h2 = fmaf(__expf(A2 * dtv), h2, u * BA[j].z);
            h3 = fmaf(__expf(A3 * dtv), h3, u * BA[j].w);
            float yp = h0 * CA[j].x + h1 * CA[j].y + h2 * CA[j].z + h3 * CA[j].w;
            yp += __shfl_xor(yp, 1);
            yp += __shfl_xor(yp, 2);
            if (sg == 0)
                y_p[(size_t)(t0 + j) * 512] =
                    __float2bfloat16((yp + Dd * xA[j]) * silu_f(zA[j]));
        }
    };
    auto compB = [&](int t0) {
#pragma unroll
        for (int j = 0; j < U; j++) {
            float dtv = dtB[j], u = dtv * xB[j];
            h0 = fmaf(__expf(A0 * dtv), h0, u * BB[j].x);
            h1 = fmaf(__expf(A1 * dtv), h1, u * BB[j].y);
            h2 = fmaf(__expf(A2 * dtv), h2, u * BB[j].z);
            h3 = fmaf(__expf(A3 * dtv), h3, u * BB[j].w);
            float yp = h0 * CB[j].x + h1 * CB[j].y + h2 * CB[j].z + h3 * CB[j].w;
            yp += __shfl_xor(yp, 1);
            yp += __shfl_xor(yp, 2);
            if (sg == 0)
                y_p[(size_t)(t0 + j) * 512] =
                    __float2bfloat16((yp + Dd * xB[j]) * silu_f(zB[j]));
        }
    };

    loadA(0);
    for (int t = 0; t < CHLEN; t += 2 * U) {
        loadB(t + U);
        compA(t);
        if (t + 2 * U < CHLEN) loadA(t + 2 * U);
        compB(t + U);
    }
}

// per-token mean/rstd for final LN
__global__ __launch_bounds__(256) void k_stats(const float* __restrict__ h,
                                               float2* __restrict__ stats) {
    int tok = blockIdx.x * 4 + (threadIdx.x >> 6);
    int lane = threadIdx.x & 63;
    float4 v = *(const float4*)&h[(size_t)tok * 256 + lane * 4];
    float sm = v.x + v.y + v.z + v.w;
    float sq = v.x * v.x + v.y * v.y + v.z * v.z + v.w * v.w;
#pragma unroll
    for (int o = 32; o; o >>= 1) {
        sm += __shfl_xor(sm, o);
        sq += __shfl_xor(sq, o);
    }
    if (lane == 0) {
        float m = sm * (1.f / 256.f);
        float var = sq * (1.f / 256.f) - m * m;
        stats[tok] = make_float2(m, rsqrtf(var + 1e-5f));
    }
}

__global__ __launch_bounds__(256) void k_out(const float* __restrict__ h,
                                             const float2* __restrict__ stats,
                                             const float* __restrict__ g,
                                             const float* __restrict__ bias,
                                             float* __restrict__ out) {
    int b = blockIdx.x >> 3;
    int chunk = blockIdx.x & 7;
    int d = threadIdx.x;
    float accv = 0.f;
    for (int l = chunk * 128; l < chunk * 128 + 128; l++) {
        float2 st = stats[b * 1024 + l];
        accv += (h[((size_t)b * 1024 + l) * 256 + d] - st.x) * st.y;
    }
    float res = accv * g[d] * (1.f / 1024.f);
    if (chunk == 0) res += bias[d];
    atomicAdd(&out[b * 256 + d], res);
}

// ---------------- launch ----------------

extern "C" void kernel_launch(void* const* d_in, const int* in_sizes, int n_in,
                              void* d_out, int out_size, void* d_ws, size_t ws_size,
                              hipStream_t stream) {
    const float* x       = (const float*)d_in[0];
    const float* w_in    = (const float*)d_in[1];
    const float* b_in    = (const float*)d_in[2];
    const float* ln_in_g = (const float*)d_in[3];
    const float* ln_in_b = (const float*)d_in[4];
    const float* ln_g    = (const float*)d_in[5];
    const float* ln_b    = (const float*)d_in[6];
    const float* W_inproj= (const float*)d_in[7];
    const float* conv_w  = (const float*)d_in[8];
    const float* conv_b  = (const float*)d_in[9];
    const float* W_dt    = (const float*)d_in[10];
    const float* b_dt    = (const float*)d_in[11];
    const float* W_B     = (const float*)d_in[12];
    const float* W_C     = (const float*)d_in[13];
    const float* A_log   = (const float*)d_in[14];
    const float* Dp      = (const float*)d_in[15];
    const float* W_out   = (const float*)d_in[16];
    const float* ln_f_g  = (const float*)d_in[17];
    const float* ln_f_b  = (const float*)d_in[18];

    float* out = (float*)d_out;

    char* p = (char*)d_ws;
    auto alloc = [&](size_t bytes) { char* r = p; p += (bytes + 255) & ~(size_t)255; return r; };

    float* h            = (float*)alloc((size_t)NTOK * 256 * 4);
    __hip_bfloat16* hn  = (__hip_bfloat16*)alloc((size_t)NTOK * 256 * 2);
    __hip_bfloat16* xbuf= (__hip_bfloat16*)alloc((size_t)NTOK * 512 * 2);
    __hip_bfloat16* zbuf= (__hip_bfloat16*)alloc((size_t)NTOK * 512 * 2);
    __hip_bfloat16* xs  = (__hip_bfloat16*)alloc((size_t)NTOK * 512 * 2);
    __hip_bfloat16* dtb = (__hip_bfloat16*)alloc((size_t)NTOK * 512 * 2);
    float* Bin          = (float*)alloc((size_t)NTOK * 16 * 4);
    float* Cin          = (float*)alloc((size_t)NTOK * 16 * 4);
    __hip_bfloat16* yb  = (__hip_bfloat16*)alloc((size_t)NTOK * 512 * 2);
    float2* stats       = (float2*)alloc((size_t)NTOK * 8);
    float* h_end        = (float*)alloc((size_t)BQ * NCHUNK * 512 * 16 * 4);
    float* H_in         = (float*)alloc((size_t)BQ * NCHUNK * 512 * 16 * 4);
    float* dtsum        = (float*)alloc((size_t)BQ * NCHUNK * 512 * 4);
    __hip_bfloat16* W1p = (__hip_bfloat16*)alloc((size_t)NLAYER * 1024 * 256 * 2);
    __hip_bfloat16* W2p = (__hip_bfloat16*)alloc((size_t)NLAYER * 640 * 512 * 2);
    __hip_bfloat16* W3p = (__hip_bfloat16*)alloc((size_t)NLAYER * 256 * 512 * 2);

    hipMemsetAsync(d_out, 0, (size_t)out_size * sizeof(float), stream);

    k_prep<<<2784, 256, 0, stream>>>(W_inproj, W_dt, W_B, W_C, W_out, W1p, W2p, W3p);

    k_inproj_ln<<<NTOK, 256, 0, stream>>>(x, w_in, b_in, ln_in_g, ln_in_b, h);

    for (int l = 0; l < NLAYER; l++) {
        k_ln<<<NTOK / 4, 256, 0, stream>>>(h, ln_g + l * 256, ln_b + l * 256, hn);

        k_mfma<0, 128><<<dim3(64, 16), 256, 0, stream>>>(
            hn, W1p + (size_t)l * 1024 * 256, xbuf, nullptr, zbuf, nullptr, 1024, 256);

        k_conv<<<(NTOK * 64) / 256, 256, 0, stream>>>(xbuf, conv_w + (size_t)l * 512 * 4,
                                                      conv_b + (size_t)l * 512, xs);

        k_mfma<1, 128><<<dim3(64, 9), 256, 0, stream>>>(
            xs, W2p + (size_t)l * 640 * 512, dtb, b_dt + (size_t)l * 512, Bin, Cin, 576, 512);

        const float* Al = A_log + (size_t)l * 512 * 16;
        k_scanA<<<1024, 256, 0, stream>>>(xs, dtb, Bin, Al, h_end, dtsum);
        k_carry<<<256, 256, 0, stream>>>(h_end, dtsum, Al, H_in);
        k_scanC<<<1024, 256, 0, stream>>>(xs, dtb, Bin, Cin, Al, H_in, zbuf,
                                          Dp + (size_t)l * 512, yb);

        k_mfma<2, 64><<<dim3(128, 4), 256, 0, stream>>>(
            yb, W3p + (size_t)l * 256 * 512, h, nullptr, nullptr, nullptr, 256, 512);
    }

    k_stats<<<NTOK / 4, 256, 0, stream>>>(h, stats);
    k_out<<<64, 256, 0, stream>>>(h, stats, ln_f_g, ln_f_b, out);
}